// Round 6
// baseline (461.994 us; speedup 1.0000x reference)
//
#include <hip/hip_runtime.h>

// Problem constants (fixed by the reference)
#define BB   4096
#define DD   768
#define EE   16
#define KDD  1536
#define KSEL 50
#define TOTP (2*BB)          // total routed pairs (top-2, distinct experts)
#define FLTEPS 1.1920929e-07f

// Encode GEMM tiling
#define TM 128
#define TN 128

typedef _Float16 half8  __attribute__((ext_vector_type(8)));
typedef _Float16 half4v __attribute__((ext_vector_type(4)));
typedef float    floatx4 __attribute__((ext_vector_type(4)));

// ---------------- workspace layout (bytes) ----------------
// counts  : int[16]              @ 0          (memset to 0 each launch)
// offsets : int[17]              @ 256
// pairTok : int[EE*BB]           @ 512
// pairW   : float[EE*BB]         @ 262656
// tokE    : int[2*BB]            @ 524800
// tokSlot : int[2*BB]            @ 557568
// f       : float[TOTP*KDD]      @ 590336     (50.3 MB)  [gather overlays tmp here]
// xh      : f16[BB*DD]           @ 50921984   (6.3 MB)
// Wench   : f16[EE*KDD*DD]       @ 57213440   (37.7 MB)
// Wdech   : f16[EE*KDD*DD]       @ 94962176   (37.7 MB)
// selVal  : float[TOTP*64]       @ 132710912  (2 MB)
// selIdx  : int[TOTP*64]         @ 134808064  (2 MB)
// selCnt  : int[TOTP]            @ 136905216
// pairE   : int[TOTP]            @ 136937984
// pairT2  : int[TOTP]            @ 136970752
// pw      : float[TOTP]          @ 137003520
// total ~137 MB

// ================= conversion kernels =================
__global__ __launch_bounds__(256) void convx_kernel(
    const float* __restrict__ x, const float* __restrict__ b_dec,
    _Float16* __restrict__ xh)
{
    int g = blockIdx.x * 256 + threadIdx.x;
    int c4 = g % (DD / 4);
    float4 v = reinterpret_cast<const float4*>(x)[g];
    float4 b = reinterpret_cast<const float4*>(b_dec)[c4];
    half4v h;
    h[0] = (_Float16)(v.x - b.x); h[1] = (_Float16)(v.y - b.y);
    h[2] = (_Float16)(v.z - b.z); h[3] = (_Float16)(v.w - b.w);
    reinterpret_cast<half4v*>(xh)[g] = h;
}

// Fused: read Wenc once, emit Wench (f16 copy) and Wdech (f16, unit-norm rows).
__global__ __launch_bounds__(256) void convwd_kernel(
    const float* __restrict__ Wenc,
    _Float16* __restrict__ Wench, _Float16* __restrict__ Wdech)
{
    const int lane = threadIdx.x & 63;
    const int row  = blockIdx.x * 4 + (threadIdx.x >> 6);
    const float* src = Wenc + (size_t)row * DD;

    float4 v[3];
    float ss = 0.f;
    #pragma unroll
    for (int c = 0; c < 3; ++c) {
        v[c] = *reinterpret_cast<const float4*>(src + c*256 + lane*4);
        ss += v[c].x*v[c].x + v[c].y*v[c].y + v[c].z*v[c].z + v[c].w*v[c].w;
    }
    #pragma unroll
    for (int o = 32; o > 0; o >>= 1) ss += __shfl_xor(ss, o, 64);
    float rn = 1.f / (sqrtf(ss) + FLTEPS);

    _Float16* de = Wench + (size_t)row * DD;
    _Float16* dd = Wdech + (size_t)row * DD;
    #pragma unroll
    for (int c = 0; c < 3; ++c) {
        half4v he, hd;
        he[0] = (_Float16)v[c].x;      he[1] = (_Float16)v[c].y;
        he[2] = (_Float16)v[c].z;      he[3] = (_Float16)v[c].w;
        hd[0] = (_Float16)(v[c].x*rn); hd[1] = (_Float16)(v[c].y*rn);
        hd[2] = (_Float16)(v[c].z*rn); hd[3] = (_Float16)(v[c].w*rn);
        *reinterpret_cast<half4v*>(de + c*256 + lane*4) = he;
        *reinterpret_cast<half4v*>(dd + c*256 + lane*4) = hd;
    }
}

// ================= Kernel 1: gating + routing =================
// 16 groups x 4 lanes: group g computes expert g's dot; each lane covers 192
// contiguous dims (48 float4). Reduce = 2 shuffles (xor 1,2), not 6.
__global__ __launch_bounds__(256) void gate_kernel(
    const float* __restrict__ x, const float* __restrict__ Wg,
    const float* __restrict__ bg, const float* __restrict__ b_gate,
    int* __restrict__ counts, int* __restrict__ pairTok, float* __restrict__ pairW,
    int* __restrict__ tokE, int* __restrict__ tokSlot)
{
    const int lane = threadIdx.x & 63;
    const int wv   = threadIdx.x >> 6;
    const int t    = blockIdx.x * 4 + wv;
    const int grp  = lane >> 2;          // expert 0..15
    const int li   = lane & 3;           // quarter 0..3

    __shared__ float lgS[4][16];

    const float4* xr4 = reinterpret_cast<const float4*>(x + (size_t)t * DD + li * 192);
    const float4* gr4 = reinterpret_cast<const float4*>(b_gate + li * 192);
    const float4* wr4 = reinterpret_cast<const float4*>(Wg + grp * DD + li * 192);

    float a4[4] = {0.f, 0.f, 0.f, 0.f};
    #pragma unroll
    for (int i = 0; i < 48; ++i) {
        float4 xv = xr4[i];
        float4 bv = gr4[i];
        float4 wvv = wr4[i];
        float* a = &a4[i & 3];
        *a = fmaf(xv.x - bv.x, wvv.x, *a);
        *a = fmaf(xv.y - bv.y, wvv.y, *a);
        *a = fmaf(xv.z - bv.z, wvv.z, *a);
        *a = fmaf(xv.w - bv.w, wvv.w, *a);
    }
    float s = (a4[0] + a4[1]) + (a4[2] + a4[3]);
    s += __shfl_xor(s, 1, 64);
    s += __shfl_xor(s, 2, 64);
    if (li == 0) lgS[wv][grp] = s + bg[grp];
    __syncthreads();   // block-uniform

    float lg[16];
    #pragma unroll
    for (int e = 0; e < 16; ++e) lg[e] = lgS[wv][e];

    int i1 = 0;
    #pragma unroll
    for (int e = 1; e < 16; ++e) if (lg[e] > lg[i1]) i1 = e;
    int i2 = (i1 == 0) ? 1 : 0;
    #pragma unroll
    for (int e = 0; e < 16; ++e) if (e != i1 && lg[e] > lg[i2]) i2 = e;
    float l3 = -1e30f;
    #pragma unroll
    for (int e = 0; e < 16; ++e) if (e != i1 && e != i2) l3 = fmaxf(l3, lg[e]);

    // near-tie at the 2-vs-3 boundary: refine all logits in fp64 (rare)
    if (lg[i2] - l3 < 1e-4f) {
        const float* xr = x + (size_t)t * DD;
        float xv[12];
        #pragma unroll
        for (int q = 0; q < 12; ++q) xv[q] = xr[lane + 64*q] - b_gate[lane + 64*q];
        #pragma unroll
        for (int e = 0; e < 16; ++e) {
            const float* wr = Wg + e * DD;
            double sd = 0.0;
            #pragma unroll
            for (int q = 0; q < 12; ++q) sd += (double)xv[q] * (double)wr[lane + 64*q];
            #pragma unroll
            for (int o = 32; o > 0; o >>= 1) sd += __shfl_xor(sd, o, 64);
            lg[e] = (float)(sd + (double)bg[e]);
        }
        i1 = 0;
        for (int e = 1; e < 16; ++e) if (lg[e] > lg[i1]) i1 = e;
        i2 = (i1 == 0) ? 1 : 0;
        for (int e = 0; e < 16; ++e) if (e != i1 && lg[e] > lg[i2]) i2 = e;
    }

    float mx = lg[0];
    #pragma unroll
    for (int e = 1; e < 16; ++e) mx = fmaxf(mx, lg[e]);
    float S = 0.f;
    #pragma unroll
    for (int e = 0; e < 16; ++e) S += expf(lg[e] - mx);
    float p1 = expf(lg[i1] - mx) / S;
    float p2 = expf(lg[i2] - mx) / S;
    float ed = expf(p2 - p1);
    float m1 = 1.f / (1.f + ed);
    float m2 = ed / (1.f + ed);

    if (lane == 0) {
        int s1 = atomicAdd(&counts[i1], 1);
        pairTok[i1 * BB + s1] = t;  pairW[i1 * BB + s1] = m1;
        tokE[2*t + 0] = i1;  tokSlot[2*t + 0] = s1;
        int s2 = atomicAdd(&counts[i2], 1);
        pairTok[i2 * BB + s2] = t;  pairW[i2 * BB + s2] = m2;
        tokE[2*t + 1] = i2;  tokSlot[2*t + 1] = s2;
    }
}

// ================= Kernel 2: prefix offsets =================
__global__ void offsets_kernel(const int* __restrict__ counts, int* __restrict__ offsets)
{
    if (threadIdx.x == 0) {
        int s = 0;
        for (int e = 0; e < EE; ++e) { offsets[e] = s; s += counts[e]; }
        offsets[EE] = s;
    }
}

// ================= Kernel 2b: compact pair metadata =================
__global__ __launch_bounds__(256) void pair_meta_kernel(
    const int* __restrict__ tokE, const int* __restrict__ tokSlot,
    const float* __restrict__ pairW, const int* __restrict__ offsets,
    int* __restrict__ pairE, int* __restrict__ pairT2, float* __restrict__ pw)
{
    int i = blockIdx.x * 256 + threadIdx.x;
    if (i >= TOTP) return;
    int t = i >> 1, j = i & 1;
    int e = tokE[2*t + j], slot = tokSlot[2*t + j];
    int p = offsets[e] + slot;
    pairE[p] = e;
    pairT2[p] = t;
    pw[p] = pairW[e * BB + slot];
}

// ================= Kernel 3: grouped f16 MFMA encode GEMM =================
__global__ __launch_bounds__(256) void encode_kernel(
    const _Float16* __restrict__ xh, const _Float16* __restrict__ Wench,
    const float* __restrict__ benc,
    const int* __restrict__ counts, const int* __restrict__ offsets,
    const int* __restrict__ pairTok, const float* __restrict__ pairW,
    float* __restrict__ f)
{
    const int e     = blockIdx.z;
    const int count = counts[e];
    const int m0    = blockIdx.y * TM;
    if (m0 >= count) return;
    const int n0 = blockIdx.x * TN;

    __shared__ __align__(16) _Float16 As[128][32];
    __shared__ __align__(16) _Float16 Bs[128][32];
    __shared__ int   toks[TM];
    __shared__ float wls[TM];

    const int tid = threadIdx.x;
    if (tid < TM) {
        int mg = m0 + tid;
        toks[tid] = (mg < count) ? pairTok[e * BB + mg] : -1;
        wls[tid]  = (mg < count) ? pairW[e * BB + mg] : 0.f;
    }
    __syncthreads();

    const int srow = tid >> 1;
    const int sseg = (tid & 1) * 16;
    const int tok  = toks[srow];
    const _Float16* arow = xh + (size_t)(tok < 0 ? 0 : tok) * DD + sseg;
    const _Float16* brow = Wench + ((size_t)e * KDD + n0 + srow) * DD + sseg;

    const int lane = tid & 63;
    const int wv   = tid >> 6;
    const int rb   = (wv >> 1) * 64;
    const int cb   = (wv & 1) * 64;
    const int lc   = lane & 15;
    const int lq   = lane >> 4;

    floatx4 acc[4][4];
    #pragma unroll
    for (int mi = 0; mi < 4; ++mi)
        #pragma unroll
        for (int nj = 0; nj < 4; ++nj)
            acc[mi][nj] = (floatx4){0.f, 0.f, 0.f, 0.f};

    for (int kt = 0; kt < DD / 32; ++kt) {
        const int koff = kt * 32;
        uint4 a0, a1, b0, b1;
        if (tok >= 0) {
            a0 = *reinterpret_cast<const uint4*>(arow + koff);
            a1 = *reinterpret_cast<const uint4*>(arow + koff + 8);
        } else {
            a0 = make_uint4(0,0,0,0); a1 = make_uint4(0,0,0,0);
        }
        b0 = *reinterpret_cast<const uint4*>(brow + koff);
        b1 = *reinterpret_cast<const uint4*>(brow + koff + 8);
        __syncthreads();
        *reinterpret_cast<uint4*>(&As[srow][sseg])     = a0;
        *reinterpret_cast<uint4*>(&As[srow][sseg + 8]) = a1;
        *reinterpret_cast<uint4*>(&Bs[srow][sseg])     = b0;
        *reinterpret_cast<uint4*>(&Bs[srow][sseg + 8]) = b1;
        __syncthreads();

        half8 af[4], bf[4];
        #pragma unroll
        for (int mi = 0; mi < 4; ++mi)
            af[mi] = *reinterpret_cast<const half8*>(&As[rb + mi*16 + lc][lq * 8]);
        #pragma unroll
        for (int nj = 0; nj < 4; ++nj)
            bf[nj] = *reinterpret_cast<const half8*>(&Bs[cb + nj*16 + lc][lq * 8]);
        #pragma unroll
        for (int mi = 0; mi < 4; ++mi)
            #pragma unroll
            for (int nj = 0; nj < 4; ++nj)
                acc[mi][nj] = __builtin_amdgcn_mfma_f32_16x16x32_f16(af[mi], bf[nj], acc[mi][nj], 0, 0, 0);
    }

    const int off = offsets[e];
    float bv[4];
    #pragma unroll
    for (int nj = 0; nj < 4; ++nj)
        bv[nj] = benc[e * KDD + n0 + cb + nj*16 + lc];

    #pragma unroll
    for (int mi = 0; mi < 4; ++mi) {
        #pragma unroll
        for (int r = 0; r < 4; ++r) {
            int ml = rb + mi*16 + lq*4 + r;
            int mg = m0 + ml;
            if (mg < count) {
                float wrow = wls[ml];
                float* frow = f + (size_t)(off + mg) * KDD + n0 + cb;
                #pragma unroll
                for (int nj = 0; nj < 4; ++nj)
                    frow[nj*16 + lc] = wrow * fmaxf(acc[mi][nj][r] + bv[nj], 0.f);
            }
        }
    }
}

// ================= Kernel 4a: top-50 selection per pair =================
// Count reductions via ballot+popc (no LDS-latency shuffle chains).
__global__ __launch_bounds__(256) void select_kernel(
    const float* __restrict__ f, const float* __restrict__ x,
    const float* __restrict__ b_dec, const float* __restrict__ Wenc,
    const float* __restrict__ benc,
    const int* __restrict__ pairE, const int* __restrict__ pairT2,
    const float* __restrict__ pw,
    float* __restrict__ selVal, int* __restrict__ selIdx, int* __restrict__ selCnt)
{
    const int lane = threadIdx.x & 63;
    const int wv   = threadIdx.x >> 6;
    const int p    = blockIdx.x * 4 + wv;

    __shared__ float dvS[4][56];
    __shared__ int   diS[4][56];
    __shared__ float cvS[4][24];
    __shared__ int   ciS[4][24];
    __shared__ int   cntS[4][2];

    const int e   = pairE[p];
    const int t   = pairT2[p];
    const float w = pw[p];
    const float* fr = f + (size_t)p * KDD;

    float v[24];
    #pragma unroll
    for (int q = 0; q < 24; ++q) v[q] = fr[lane + 64*q];

    float mxv = 0.f; int cp = 0;
    #pragma unroll
    for (int q = 0; q < 24; ++q) {
        mxv = fmaxf(mxv, v[q]);
        cp += __popcll(__ballot(v[q] > 0.f));
    }
    #pragma unroll
    for (int o = 32; o > 0; o >>= 1) mxv = fmaxf(mxv, __shfl_xor(mxv, o, 64));

    const bool simple = (cp <= KSEL);
    const float E = w * 6e-3f;                  // 15 sigma of f16-MFMA z-noise
    float lo = 0.f, hi = mxv;
    if (!simple) {
        for (int it = 0; it < 32 && (hi - lo) > 0.5f * E; ++it) {
            float mid = 0.5f * (lo + hi);
            int c = 0;
            #pragma unroll
            for (int q = 0; q < 24; ++q) c += __popcll(__ballot(v[q] > mid));
            if (c > KSEL)      lo = mid;
            else if (c < KSEL) hi = mid;
            else { lo = mid; hi = mid; break; }
        }
    }

    if (lane == 0) { cntS[wv][0] = 0; cntS[wv][1] = 0; }
    __syncthreads();

    if (simple) {
        #pragma unroll
        for (int q = 0; q < 24; ++q)
            if (v[q] > 0.f) {
                int pp = atomicAdd(&cntS[wv][0], 1);
                if (pp < 56) { dvS[wv][pp] = v[q]; diS[wv][pp] = lane + 64*q; }
            }
    } else {
        const float thD = hi + 2.f * E;
        const float thC = lo - 2.f * E;
        #pragma unroll
        for (int q = 0; q < 24; ++q) {
            float vq = v[q];
            if (vq > thD) {
                int pp = atomicAdd(&cntS[wv][0], 1);
                if (pp < 56) { dvS[wv][pp] = vq; diS[wv][pp] = lane + 64*q; }
            } else if (vq > thC) {
                int pp = atomicAdd(&cntS[wv][1], 1);
                if (pp < 24) { cvS[wv][pp] = vq; ciS[wv][pp] = lane + 64*q; }
            }
        }
    }
    __syncthreads();

    int nD = cntS[wv][0]; if (nD > 56) nD = 56;
    int nC = cntS[wv][1]; if (nC > 24) nC = 24;
    int need = simple ? 0 : (KSEL - nD);
    if (need < 0) need = 0;
    if (need > nC) need = nC;

    unsigned long long cmask = 0ull;
    if (need > 0 && need < nC) {
        const float* xr = x + (size_t)t * DD;
        double myz = -1.0e300;
        int myidx = 0x7fffffff;
        for (int c = 0; c < nC; ++c) {
            int idx = ciS[wv][c];
            const float* wr = Wenc + ((size_t)e * KDD + idx) * DD;
            double s = 0.0;
            #pragma unroll
            for (int d = 0; d < 12; ++d)
                s += ((double)xr[lane + 64*d] - (double)b_dec[lane + 64*d]) * (double)wr[lane + 64*d];
            #pragma unroll
            for (int o = 32; o > 0; o >>= 1) s += __shfl_xor(s, o, 64);
            if (lane == c) { myz = s + (double)benc[e * KDD + idx]; myidx = idx; }
        }
        bool used = false;
        for (int s2 = 0; s2 < need; ++s2) {
            bool pres = (lane < nC) && !used;
            double bz = pres ? myz : -1.0e301;
            int bl = pres ? lane : 127;
            int bi = pres ? myidx : 0x7fffffff;
            #pragma unroll
            for (int o = 32; o > 0; o >>= 1) {
                double oz = __shfl_xor(bz, o, 64);
                int    ol = __shfl_xor(bl, o, 64);
                int    oi = __shfl_xor(bi, o, 64);
                if (oz > bz || (oz == bz && oi < bi)) { bz = oz; bl = ol; bi = oi; }
            }
            if (lane == bl) used = true;
            if (bl < 64) cmask |= (1ull << bl);
        }
    } else if (need == nC && nC > 0) {
        cmask = (1ull << nC) - 1ull;
    }

    if (lane == 0) {
        int k = nD; if (k > KSEL) k = KSEL;
        for (int c = 0; c < nC && k < KSEL; ++c)
            if ((cmask >> c) & 1ull) { dvS[wv][k] = cvS[wv][c]; diS[wv][k] = ciS[wv][c]; ++k; }
        cntS[wv][0] = k;
    }
    __syncthreads();

    int cnt = cntS[wv][0];
    if (lane < cnt) {
        selVal[(size_t)p * 64 + lane] = dvS[wv][lane];
        selIdx[(size_t)p * 64 + lane] = diS[wv][lane];
    }
    if (lane == 0) selCnt[p] = cnt;
}

// ================= Kernel 4b: expert-grouped gather, 8-row unroll, no atomics =================
__global__ __launch_bounds__(256) void gather_kernel(
    const float* __restrict__ selVal, const int* __restrict__ selIdx,
    const int* __restrict__ selCnt, const int* __restrict__ offsets,
    const _Float16* __restrict__ Wdech, float* __restrict__ tmp)
{
    const int lane = threadIdx.x & 63;
    const int wv   = threadIdx.x >> 6;
    const int xg   = blockIdx.x;
    const int base = offsets[2*xg];
    const int mid  = offsets[2*xg + 1];
    const int end  = offsets[2*xg + 2];
    const int cntg = end - base;

    for (int pl = blockIdx.y * 4 + wv; pl < cntg; pl += gridDim.y * 4) {
        const int p   = base + pl;
        const int e   = (p < mid) ? (2*xg) : (2*xg + 1);
        const int cnt = selCnt[p];

        float myVal = 0.f; int myIdx = 0;
        if (lane < cnt) {
            myVal = selVal[(size_t)p * 64 + lane];
            myIdx = selIdx[(size_t)p * 64 + lane];
        }

        const _Float16* wb = Wdech + (size_t)e * KDD * DD;
        float acc[12];
        #pragma unroll
        for (int k = 0; k < 12; ++k) acc[k] = 0.f;

        const int padded = (cnt + 7) & ~7;
        for (int r = 0; r < padded; r += 8) {
            float vv[8];
            const _Float16* rp[8];
            #pragma unroll
            for (int u = 0; u < 8; ++u) {
                vv[u] = __shfl(myVal, r + u);
                int iu = __shfl(myIdx, r + u);
                rp[u] = wb + (size_t)iu * DD + lane * 4;
            }
            half4v h[8][3];
            #pragma unroll
            for (int u = 0; u < 8; ++u) {
                h[u][0] = *reinterpret_cast<const half4v*>(rp[u]);
                h[u][1] = *reinterpret_cast<const half4v*>(rp[u] + 256);
                h[u][2] = *reinterpret_cast<const half4v*>(rp[u] + 512);
            }
            #pragma unroll
            for (int u = 0; u < 8; ++u)
                #pragma unroll
                for (int c = 0; c < 3; ++c)
                    #pragma unroll
                    for (int k = 0; k < 4; ++k)
                        acc[c*4 + k] = fmaf(vv[u], (float)h[u][c][k], acc[c*4 + k]);
        }

        float* orow = tmp + (size_t)p * DD + lane * 4;
        #pragma unroll
        for (int c = 0; c < 3; ++c) {
            float4 o = make_float4(acc[c*4+0], acc[c*4+1], acc[c*4+2], acc[c*4+3]);
            *reinterpret_cast<float4*>(orow + c * 256) = o;
        }
    }
}

// ================= Kernel 4c: combine two pair rows + b_dec -> out =================
__global__ __launch_bounds__(256) void combine_kernel(
    const float* __restrict__ tmp, const float* __restrict__ b_dec,
    const int* __restrict__ tokE, const int* __restrict__ tokSlot,
    const int* __restrict__ offsets, float* __restrict__ out)
{
    const int lane = threadIdx.x & 63;
    const int t    = blockIdx.x * 4 + (threadIdx.x >> 6);

    const int p0 = offsets[tokE[2*t + 0]] + tokSlot[2*t + 0];
    const int p1 = offsets[tokE[2*t + 1]] + tokSlot[2*t + 1];

    const float* r0 = tmp + (size_t)p0 * DD + lane * 4;
    const float* r1 = tmp + (size_t)p1 * DD + lane * 4;
    float* orow = out + (size_t)t * DD + lane * 4;
    #pragma unroll
    for (int c = 0; c < 3; ++c) {
        float4 a = *reinterpret_cast<const float4*>(r0 + c * 256);
        float4 b = *reinterpret_cast<const float4*>(r1 + c * 256);
        float4 d = *reinterpret_cast<const float4*>(b_dec + c * 256 + lane * 4);
        *reinterpret_cast<float4*>(orow + c * 256) =
            make_float4(a.x + b.x + d.x, a.y + b.y + d.y, a.z + b.z + d.z, a.w + b.w + d.w);
    }
}

// ================= host launcher =================
extern "C" void kernel_launch(void* const* d_in, const int* in_sizes, int n_in,
                              void* d_out, int out_size, void* d_ws, size_t ws_size,
                              hipStream_t stream)
{
    const float* x      = (const float*)d_in[0];
    const float* Wg     = (const float*)d_in[1];
    const float* bg     = (const float*)d_in[2];
    const float* b_gate = (const float*)d_in[3];
    const float* b_dec  = (const float*)d_in[4];
    const float* Wenc   = (const float*)d_in[5];
    const float* benc   = (const float*)d_in[6];
    float* out = (float*)d_out;

    char* ws = (char*)d_ws;
    int*      counts  = (int*)(ws + 0);
    int*      offsets = (int*)(ws + 256);
    int*      pairTok = (int*)(ws + 512);
    float*    pairW   = (float*)(ws + 262656);
    int*      tokE    = (int*)(ws + 524800);
    int*      tokSlot = (int*)(ws + 557568);
    float*    f       = (float*)(ws + 590336);
    float*    tmp     = f;   // overlaid: f is dead after select_kernel
    _Float16* xh      = (_Float16*)(ws + 50921984);
    _Float16* Wench   = (_Float16*)(ws + 57213440);
    _Float16* Wdech   = (_Float16*)(ws + 94962176);
    float*    selVal  = (float*)(ws + 132710912);
    int*      selIdx  = (int*)(ws + 134808064);
    int*      selCnt  = (int*)(ws + 136905216);
    int*      pairE   = (int*)(ws + 136937984);
    int*      pairT2  = (int*)(ws + 136970752);
    float*    pw      = (float*)(ws + 137003520);

    hipMemsetAsync(counts, 0, 64, stream);
    convx_kernel<<<3072, 256, 0, stream>>>(x, b_dec, xh);
    convwd_kernel<<<(EE*KDD)/4, 256, 0, stream>>>(Wenc, Wench, Wdech);
    gate_kernel<<<BB/4, 256, 0, stream>>>(x, Wg, bg, b_gate, counts, pairTok, pairW, tokE, tokSlot);
    offsets_kernel<<<1, 64, 0, stream>>>(counts, offsets);
    pair_meta_kernel<<<TOTP/256, 256, 0, stream>>>(tokE, tokSlot, pairW, offsets, pairE, pairT2, pw);
    encode_kernel<<<dim3(KDD/TN, BB/TM, EE), 256, 0, stream>>>(xh, Wench, benc,
                                                               counts, offsets, pairTok, pairW, f);
    select_kernel<<<TOTP/4, 256, 0, stream>>>(f, x, b_dec, Wenc, benc,
                                              pairE, pairT2, pw, selVal, selIdx, selCnt);
    gather_kernel<<<dim3(8, 320), 256, 0, stream>>>(selVal, selIdx, selCnt,
                                                    offsets, Wdech, tmp);
    combine_kernel<<<BB/4, 256, 0, stream>>>(tmp, b_dec, tokE, tokSlot, offsets, out);
}

// Round 7
// 406.665 us; speedup vs baseline: 1.1361x; 1.1361x over previous
//
#include <hip/hip_runtime.h>

// Problem constants (fixed by the reference)
#define BB   4096
#define DD   768
#define EE   16
#define KDD  1536
#define KSEL 50
#define TOTP (2*BB)          // total routed pairs (top-2, distinct experts)
#define FLTEPS 1.1920929e-07f

// Encode GEMM tiling
#define TM 128
#define TN 128

typedef _Float16 half8  __attribute__((ext_vector_type(8)));
typedef _Float16 half4v __attribute__((ext_vector_type(4)));
typedef float    floatx4 __attribute__((ext_vector_type(4)));

// ---------------- workspace layout (bytes) ----------------
// counts  : int[16]              @ 0          (memset to 0 each launch)
// offsets : int[17]              @ 256
// pairTok : int[EE*BB]           @ 512
// pairW   : float[EE*BB]         @ 262656
// tokE    : int[2*BB]            @ 524800
// tokSlot : int[2*BB]            @ 557568
// f       : float[TOTP*KDD]      @ 590336     (50.3 MB)  [gather overlays tmp here]
// xh      : f16[BB*DD]           @ 50921984   (6.3 MB)
// Wench   : f16[EE*KDD*DD]       @ 57213440   (37.7 MB)
// Wdech   : f16[EE*KDD*DD]       @ 94962176   (37.7 MB)
// selVal  : float[TOTP*64]       @ 132710912  (2 MB)
// selIdx  : int[TOTP*64]         @ 134808064  (2 MB)
// selCnt  : int[TOTP]            @ 136905216
// pairE   : int[TOTP]            @ 136937984
// pairT2  : int[TOTP]            @ 136970752
// pw      : float[TOTP]          @ 137003520
// tokW    : float[2*BB]          @ 137036288
// total ~137.1 MB

// ================= conversion kernels =================
__global__ __launch_bounds__(256) void convx_kernel(
    const float* __restrict__ x, const float* __restrict__ b_dec,
    _Float16* __restrict__ xh)
{
    int g = blockIdx.x * 256 + threadIdx.x;
    int c4 = g % (DD / 4);
    float4 v = reinterpret_cast<const float4*>(x)[g];
    float4 b = reinterpret_cast<const float4*>(b_dec)[c4];
    half4v h;
    h[0] = (_Float16)(v.x - b.x); h[1] = (_Float16)(v.y - b.y);
    h[2] = (_Float16)(v.z - b.z); h[3] = (_Float16)(v.w - b.w);
    reinterpret_cast<half4v*>(xh)[g] = h;
}

// Fused: read Wenc once, emit Wench (f16 copy) and Wdech (f16, unit-norm rows).
__global__ __launch_bounds__(256) void convwd_kernel(
    const float* __restrict__ Wenc,
    _Float16* __restrict__ Wench, _Float16* __restrict__ Wdech)
{
    const int lane = threadIdx.x & 63;
    const int row  = blockIdx.x * 4 + (threadIdx.x >> 6);
    const float* src = Wenc + (size_t)row * DD;

    float4 v[3];
    float ss = 0.f;
    #pragma unroll
    for (int c = 0; c < 3; ++c) {
        v[c] = *reinterpret_cast<const float4*>(src + c*256 + lane*4);
        ss += v[c].x*v[c].x + v[c].y*v[c].y + v[c].z*v[c].z + v[c].w*v[c].w;
    }
    #pragma unroll
    for (int o = 32; o > 0; o >>= 1) ss += __shfl_xor(ss, o, 64);
    float rn = 1.f / (sqrtf(ss) + FLTEPS);

    _Float16* de = Wench + (size_t)row * DD;
    _Float16* dd = Wdech + (size_t)row * DD;
    #pragma unroll
    for (int c = 0; c < 3; ++c) {
        half4v he, hd;
        he[0] = (_Float16)v[c].x;      he[1] = (_Float16)v[c].y;
        he[2] = (_Float16)v[c].z;      he[3] = (_Float16)v[c].w;
        hd[0] = (_Float16)(v[c].x*rn); hd[1] = (_Float16)(v[c].y*rn);
        hd[2] = (_Float16)(v[c].z*rn); hd[3] = (_Float16)(v[c].w*rn);
        *reinterpret_cast<half4v*>(de + c*256 + lane*4) = he;
        *reinterpret_cast<half4v*>(dd + c*256 + lane*4) = hd;
    }
}

// ================= Kernel 1: gating (NO atomics — just top-2 + weights) =================
// 16 groups x 4 lanes: group g computes expert g's dot; each lane covers 192
// contiguous dims (48 float4). Reduce = 2 shuffles (xor 1,2).
__global__ __launch_bounds__(256) void gate_kernel(
    const float* __restrict__ x, const float* __restrict__ Wg,
    const float* __restrict__ bg, const float* __restrict__ b_gate,
    int* __restrict__ tokE, float* __restrict__ tokW)
{
    const int lane = threadIdx.x & 63;
    const int wv   = threadIdx.x >> 6;
    const int t    = blockIdx.x * 4 + wv;
    const int grp  = lane >> 2;          // expert 0..15
    const int li   = lane & 3;           // quarter 0..3

    __shared__ float lgS[4][16];

    const float4* xr4 = reinterpret_cast<const float4*>(x + (size_t)t * DD + li * 192);
    const float4* gr4 = reinterpret_cast<const float4*>(b_gate + li * 192);
    const float4* wr4 = reinterpret_cast<const float4*>(Wg + grp * DD + li * 192);

    float a4[4] = {0.f, 0.f, 0.f, 0.f};
    #pragma unroll
    for (int i = 0; i < 48; ++i) {
        float4 xv = xr4[i];
        float4 bv = gr4[i];
        float4 wvv = wr4[i];
        float* a = &a4[i & 3];
        *a = fmaf(xv.x - bv.x, wvv.x, *a);
        *a = fmaf(xv.y - bv.y, wvv.y, *a);
        *a = fmaf(xv.z - bv.z, wvv.z, *a);
        *a = fmaf(xv.w - bv.w, wvv.w, *a);
    }
    float s = (a4[0] + a4[1]) + (a4[2] + a4[3]);
    s += __shfl_xor(s, 1, 64);
    s += __shfl_xor(s, 2, 64);
    if (li == 0) lgS[wv][grp] = s + bg[grp];
    __syncthreads();   // block-uniform

    float lg[16];
    #pragma unroll
    for (int e = 0; e < 16; ++e) lg[e] = lgS[wv][e];

    int i1 = 0;
    #pragma unroll
    for (int e = 1; e < 16; ++e) if (lg[e] > lg[i1]) i1 = e;
    int i2 = (i1 == 0) ? 1 : 0;
    #pragma unroll
    for (int e = 0; e < 16; ++e) if (e != i1 && lg[e] > lg[i2]) i2 = e;
    float l3 = -1e30f;
    #pragma unroll
    for (int e = 0; e < 16; ++e) if (e != i1 && e != i2) l3 = fmaxf(l3, lg[e]);

    // near-tie at the 2-vs-3 boundary: refine all logits in fp64 (rare)
    if (lg[i2] - l3 < 1e-4f) {
        const float* xr = x + (size_t)t * DD;
        float xv[12];
        #pragma unroll
        for (int q = 0; q < 12; ++q) xv[q] = xr[lane + 64*q] - b_gate[lane + 64*q];
        #pragma unroll
        for (int e = 0; e < 16; ++e) {
            const float* wr = Wg + e * DD;
            double sd = 0.0;
            #pragma unroll
            for (int q = 0; q < 12; ++q) sd += (double)xv[q] * (double)wr[lane + 64*q];
            #pragma unroll
            for (int o = 32; o > 0; o >>= 1) sd += __shfl_xor(sd, o, 64);
            lg[e] = (float)(sd + (double)bg[e]);
        }
        i1 = 0;
        for (int e = 1; e < 16; ++e) if (lg[e] > lg[i1]) i1 = e;
        i2 = (i1 == 0) ? 1 : 0;
        for (int e = 0; e < 16; ++e) if (e != i1 && lg[e] > lg[i2]) i2 = e;
    }

    float mx = lg[0];
    #pragma unroll
    for (int e = 1; e < 16; ++e) mx = fmaxf(mx, lg[e]);
    float S = 0.f;
    #pragma unroll
    for (int e = 0; e < 16; ++e) S += expf(lg[e] - mx);
    float p1 = expf(lg[i1] - mx) / S;
    float p2 = expf(lg[i2] - mx) / S;
    float ed = expf(p2 - p1);
    float m1 = 1.f / (1.f + ed);
    float m2 = ed / (1.f + ed);

    if (lane == 0) {
        tokE[2*t + 0] = i1;  tokW[2*t + 0] = m1;
        tokE[2*t + 1] = i2;  tokW[2*t + 1] = m2;
    }
}

// ================= Kernel 1b: routing via LDS histogram (128 global atomics total) =================
__global__ __launch_bounds__(1024) void route_kernel(
    const int* __restrict__ tokE, const float* __restrict__ tokW,
    int* __restrict__ counts, int* __restrict__ pairTok,
    float* __restrict__ pairW, int* __restrict__ tokSlot)
{
    __shared__ int hist[EE];
    __shared__ int base[EE];
    const int tid = threadIdx.x;
    if (tid < EE) hist[tid] = 0;
    __syncthreads();

    const int i = blockIdx.x * 1024 + tid;       // pair id = 2t+j
    const int e = tokE[i];
    const int lr = atomicAdd(&hist[e], 1);       // LDS atomic — bank-local
    __syncthreads();

    if (tid < EE) base[tid] = atomicAdd(&counts[tid], hist[tid]);
    __syncthreads();

    const int slot = base[e] + lr;
    pairTok[e * BB + slot] = i >> 1;
    pairW[e * BB + slot]   = tokW[i];
    tokSlot[i] = slot;
}

// ================= Kernel 2: prefix offsets =================
__global__ void offsets_kernel(const int* __restrict__ counts, int* __restrict__ offsets)
{
    if (threadIdx.x == 0) {
        int s = 0;
        for (int e = 0; e < EE; ++e) { offsets[e] = s; s += counts[e]; }
        offsets[EE] = s;
    }
}

// ================= Kernel 2b: compact pair metadata =================
__global__ __launch_bounds__(256) void pair_meta_kernel(
    const int* __restrict__ tokE, const int* __restrict__ tokSlot,
    const float* __restrict__ pairW, const int* __restrict__ offsets,
    int* __restrict__ pairE, int* __restrict__ pairT2, float* __restrict__ pw)
{
    int i = blockIdx.x * 256 + threadIdx.x;
    if (i >= TOTP) return;
    int t = i >> 1, j = i & 1;
    int e = tokE[2*t + j], slot = tokSlot[2*t + j];
    int p = offsets[e] + slot;
    pairE[p] = e;
    pairT2[p] = t;
    pw[p] = pairW[e * BB + slot];
}

// ================= Kernel 3: grouped f16 MFMA encode GEMM =================
__global__ __launch_bounds__(256) void encode_kernel(
    const _Float16* __restrict__ xh, const _Float16* __restrict__ Wench,
    const float* __restrict__ benc,
    const int* __restrict__ counts, const int* __restrict__ offsets,
    const int* __restrict__ pairTok, const float* __restrict__ pairW,
    float* __restrict__ f)
{
    const int e     = blockIdx.z;
    const int count = counts[e];
    const int m0    = blockIdx.y * TM;
    if (m0 >= count) return;
    const int n0 = blockIdx.x * TN;

    __shared__ __align__(16) _Float16 As[128][32];
    __shared__ __align__(16) _Float16 Bs[128][32];
    __shared__ int   toks[TM];
    __shared__ float wls[TM];

    const int tid = threadIdx.x;
    if (tid < TM) {
        int mg = m0 + tid;
        toks[tid] = (mg < count) ? pairTok[e * BB + mg] : -1;
        wls[tid]  = (mg < count) ? pairW[e * BB + mg] : 0.f;
    }
    __syncthreads();

    const int srow = tid >> 1;
    const int sseg = (tid & 1) * 16;
    const int tok  = toks[srow];
    const _Float16* arow = xh + (size_t)(tok < 0 ? 0 : tok) * DD + sseg;
    const _Float16* brow = Wench + ((size_t)e * KDD + n0 + srow) * DD + sseg;

    const int lane = tid & 63;
    const int wv   = tid >> 6;
    const int rb   = (wv >> 1) * 64;
    const int cb   = (wv & 1) * 64;
    const int lc   = lane & 15;
    const int lq   = lane >> 4;

    floatx4 acc[4][4];
    #pragma unroll
    for (int mi = 0; mi < 4; ++mi)
        #pragma unroll
        for (int nj = 0; nj < 4; ++nj)
            acc[mi][nj] = (floatx4){0.f, 0.f, 0.f, 0.f};

    for (int kt = 0; kt < DD / 32; ++kt) {
        const int koff = kt * 32;
        uint4 a0, a1, b0, b1;
        if (tok >= 0) {
            a0 = *reinterpret_cast<const uint4*>(arow + koff);
            a1 = *reinterpret_cast<const uint4*>(arow + koff + 8);
        } else {
            a0 = make_uint4(0,0,0,0); a1 = make_uint4(0,0,0,0);
        }
        b0 = *reinterpret_cast<const uint4*>(brow + koff);
        b1 = *reinterpret_cast<const uint4*>(brow + koff + 8);
        __syncthreads();
        *reinterpret_cast<uint4*>(&As[srow][sseg])     = a0;
        *reinterpret_cast<uint4*>(&As[srow][sseg + 8]) = a1;
        *reinterpret_cast<uint4*>(&Bs[srow][sseg])     = b0;
        *reinterpret_cast<uint4*>(&Bs[srow][sseg + 8]) = b1;
        __syncthreads();

        half8 af[4], bf[4];
        #pragma unroll
        for (int mi = 0; mi < 4; ++mi)
            af[mi] = *reinterpret_cast<const half8*>(&As[rb + mi*16 + lc][lq * 8]);
        #pragma unroll
        for (int nj = 0; nj < 4; ++nj)
            bf[nj] = *reinterpret_cast<const half8*>(&Bs[cb + nj*16 + lc][lq * 8]);
        #pragma unroll
        for (int mi = 0; mi < 4; ++mi)
            #pragma unroll
            for (int nj = 0; nj < 4; ++nj)
                acc[mi][nj] = __builtin_amdgcn_mfma_f32_16x16x32_f16(af[mi], bf[nj], acc[mi][nj], 0, 0, 0);
    }

    const int off = offsets[e];
    float bv[4];
    #pragma unroll
    for (int nj = 0; nj < 4; ++nj)
        bv[nj] = benc[e * KDD + n0 + cb + nj*16 + lc];

    #pragma unroll
    for (int mi = 0; mi < 4; ++mi) {
        #pragma unroll
        for (int r = 0; r < 4; ++r) {
            int ml = rb + mi*16 + lq*4 + r;
            int mg = m0 + ml;
            if (mg < count) {
                float wrow = wls[ml];
                float* frow = f + (size_t)(off + mg) * KDD + n0 + cb;
                #pragma unroll
                for (int nj = 0; nj < 4; ++nj)
                    frow[nj*16 + lc] = wrow * fmaxf(acc[mi][nj][r] + bv[nj], 0.f);
            }
        }
    }
}

// ================= Kernel 4a: top-50 selection per pair =================
__global__ __launch_bounds__(256) void select_kernel(
    const float* __restrict__ f, const float* __restrict__ x,
    const float* __restrict__ b_dec, const float* __restrict__ Wenc,
    const float* __restrict__ benc,
    const int* __restrict__ pairE, const int* __restrict__ pairT2,
    const float* __restrict__ pw,
    float* __restrict__ selVal, int* __restrict__ selIdx, int* __restrict__ selCnt)
{
    const int lane = threadIdx.x & 63;
    const int wv   = threadIdx.x >> 6;
    const int p    = blockIdx.x * 4 + wv;

    __shared__ float dvS[4][56];
    __shared__ int   diS[4][56];
    __shared__ float cvS[4][24];
    __shared__ int   ciS[4][24];
    __shared__ int   cntS[4][2];

    const int e   = pairE[p];
    const int t   = pairT2[p];
    const float w = pw[p];
    const float* fr = f + (size_t)p * KDD;

    float v[24];
    #pragma unroll
    for (int q = 0; q < 24; ++q) v[q] = fr[lane + 64*q];

    float mxv = 0.f; int cp = 0;
    #pragma unroll
    for (int q = 0; q < 24; ++q) {
        mxv = fmaxf(mxv, v[q]);
        cp += __popcll(__ballot(v[q] > 0.f));
    }
    #pragma unroll
    for (int o = 32; o > 0; o >>= 1) mxv = fmaxf(mxv, __shfl_xor(mxv, o, 64));

    const bool simple = (cp <= KSEL);
    const float E = w * 6e-3f;                  // 15 sigma of f16-MFMA z-noise
    float lo = 0.f, hi = mxv;
    if (!simple) {
        for (int it = 0; it < 32 && (hi - lo) > 0.5f * E; ++it) {
            float mid = 0.5f * (lo + hi);
            int c = 0;
            #pragma unroll
            for (int q = 0; q < 24; ++q) c += __popcll(__ballot(v[q] > mid));
            if (c > KSEL)      lo = mid;
            else if (c < KSEL) hi = mid;
            else { lo = mid; hi = mid; break; }
        }
    }

    if (lane == 0) { cntS[wv][0] = 0; cntS[wv][1] = 0; }
    __syncthreads();

    if (simple) {
        #pragma unroll
        for (int q = 0; q < 24; ++q)
            if (v[q] > 0.f) {
                int pp = atomicAdd(&cntS[wv][0], 1);
                if (pp < 56) { dvS[wv][pp] = v[q]; diS[wv][pp] = lane + 64*q; }
            }
    } else {
        const float thD = hi + 2.f * E;
        const float thC = lo - 2.f * E;
        #pragma unroll
        for (int q = 0; q < 24; ++q) {
            float vq = v[q];
            if (vq > thD) {
                int pp = atomicAdd(&cntS[wv][0], 1);
                if (pp < 56) { dvS[wv][pp] = vq; diS[wv][pp] = lane + 64*q; }
            } else if (vq > thC) {
                int pp = atomicAdd(&cntS[wv][1], 1);
                if (pp < 24) { cvS[wv][pp] = vq; ciS[wv][pp] = lane + 64*q; }
            }
        }
    }
    __syncthreads();

    int nD = cntS[wv][0]; if (nD > 56) nD = 56;
    int nC = cntS[wv][1]; if (nC > 24) nC = 24;
    int need = simple ? 0 : (KSEL - nD);
    if (need < 0) need = 0;
    if (need > nC) need = nC;

    unsigned long long cmask = 0ull;
    if (need > 0 && need < nC) {
        const float* xr = x + (size_t)t * DD;
        double myz = -1.0e300;
        int myidx = 0x7fffffff;
        for (int c = 0; c < nC; ++c) {
            int idx = ciS[wv][c];
            const float* wr = Wenc + ((size_t)e * KDD + idx) * DD;
            double s = 0.0;
            #pragma unroll
            for (int d = 0; d < 12; ++d)
                s += ((double)xr[lane + 64*d] - (double)b_dec[lane + 64*d]) * (double)wr[lane + 64*d];
            #pragma unroll
            for (int o = 32; o > 0; o >>= 1) s += __shfl_xor(s, o, 64);
            if (lane == c) { myz = s + (double)benc[e * KDD + idx]; myidx = idx; }
        }
        bool used = false;
        for (int s2 = 0; s2 < need; ++s2) {
            bool pres = (lane < nC) && !used;
            double bz = pres ? myz : -1.0e301;
            int bl = pres ? lane : 127;
            int bi = pres ? myidx : 0x7fffffff;
            #pragma unroll
            for (int o = 32; o > 0; o >>= 1) {
                double oz = __shfl_xor(bz, o, 64);
                int    ol = __shfl_xor(bl, o, 64);
                int    oi = __shfl_xor(bi, o, 64);
                if (oz > bz || (oz == bz && oi < bi)) { bz = oz; bl = ol; bi = oi; }
            }
            if (lane == bl) used = true;
            if (bl < 64) cmask |= (1ull << bl);
        }
    } else if (need == nC && nC > 0) {
        cmask = (1ull << nC) - 1ull;
    }

    if (lane == 0) {
        int k = nD; if (k > KSEL) k = KSEL;
        for (int c = 0; c < nC && k < KSEL; ++c)
            if ((cmask >> c) & 1ull) { dvS[wv][k] = cvS[wv][c]; diS[wv][k] = ciS[wv][c]; ++k; }
        cntS[wv][0] = k;
    }
    __syncthreads();

    int cnt = cntS[wv][0];
    if (lane < cnt) {
        selVal[(size_t)p * 64 + lane] = dvS[wv][lane];
        selIdx[(size_t)p * 64 + lane] = diS[wv][lane];
    }
    if (lane == 0) selCnt[p] = cnt;
}

// ================= Kernel 4b: expert-grouped gather, 8-row unroll, no atomics =================
__global__ __launch_bounds__(256) void gather_kernel(
    const float* __restrict__ selVal, const int* __restrict__ selIdx,
    const int* __restrict__ selCnt, const int* __restrict__ offsets,
    const _Float16* __restrict__ Wdech, float* __restrict__ tmp)
{
    const int lane = threadIdx.x & 63;
    const int wv   = threadIdx.x >> 6;
    const int xg   = blockIdx.x;
    const int base = offsets[2*xg];
    const int mid  = offsets[2*xg + 1];
    const int end  = offsets[2*xg + 2];
    const int cntg = end - base;

    for (int pl = blockIdx.y * 4 + wv; pl < cntg; pl += gridDim.y * 4) {
        const int p   = base + pl;
        const int e   = (p < mid) ? (2*xg) : (2*xg + 1);
        const int cnt = selCnt[p];

        float myVal = 0.f; int myIdx = 0;
        if (lane < cnt) {
            myVal = selVal[(size_t)p * 64 + lane];
            myIdx = selIdx[(size_t)p * 64 + lane];
        }

        const _Float16* wb = Wdech + (size_t)e * KDD * DD;
        float acc[12];
        #pragma unroll
        for (int k = 0; k < 12; ++k) acc[k] = 0.f;

        const int padded = (cnt + 7) & ~7;
        for (int r = 0; r < padded; r += 8) {
            float vv[8];
            const _Float16* rp[8];
            #pragma unroll
            for (int u = 0; u < 8; ++u) {
                vv[u] = __shfl(myVal, r + u);
                int iu = __shfl(myIdx, r + u);
                rp[u] = wb + (size_t)iu * DD + lane * 4;
            }
            half4v h[8][3];
            #pragma unroll
            for (int u = 0; u < 8; ++u) {
                h[u][0] = *reinterpret_cast<const half4v*>(rp[u]);
                h[u][1] = *reinterpret_cast<const half4v*>(rp[u] + 256);
                h[u][2] = *reinterpret_cast<const half4v*>(rp[u] + 512);
            }
            #pragma unroll
            for (int u = 0; u < 8; ++u)
                #pragma unroll
                for (int c = 0; c < 3; ++c)
                    #pragma unroll
                    for (int k = 0; k < 4; ++k)
                        acc[c*4 + k] = fmaf(vv[u], (float)h[u][c][k], acc[c*4 + k]);
        }

        float* orow = tmp + (size_t)p * DD + lane * 4;
        #pragma unroll
        for (int c = 0; c < 3; ++c) {
            float4 o = make_float4(acc[c*4+0], acc[c*4+1], acc[c*4+2], acc[c*4+3]);
            *reinterpret_cast<float4*>(orow + c * 256) = o;
        }
    }
}

// ================= Kernel 4c: combine two pair rows + b_dec -> out =================
__global__ __launch_bounds__(256) void combine_kernel(
    const float* __restrict__ tmp, const float* __restrict__ b_dec,
    const int* __restrict__ tokE, const int* __restrict__ tokSlot,
    const int* __restrict__ offsets, float* __restrict__ out)
{
    const int lane = threadIdx.x & 63;
    const int t    = blockIdx.x * 4 + (threadIdx.x >> 6);

    const int p0 = offsets[tokE[2*t + 0]] + tokSlot[2*t + 0];
    const int p1 = offsets[tokE[2*t + 1]] + tokSlot[2*t + 1];

    const float* r0 = tmp + (size_t)p0 * DD + lane * 4;
    const float* r1 = tmp + (size_t)p1 * DD + lane * 4;
    float* orow = out + (size_t)t * DD + lane * 4;
    #pragma unroll
    for (int c = 0; c < 3; ++c) {
        float4 a = *reinterpret_cast<const float4*>(r0 + c * 256);
        float4 b = *reinterpret_cast<const float4*>(r1 + c * 256);
        float4 d = *reinterpret_cast<const float4*>(b_dec + c * 256 + lane * 4);
        *reinterpret_cast<float4*>(orow + c * 256) =
            make_float4(a.x + b.x + d.x, a.y + b.y + d.y, a.z + b.z + d.z, a.w + b.w + d.w);
    }
}

// ================= host launcher =================
extern "C" void kernel_launch(void* const* d_in, const int* in_sizes, int n_in,
                              void* d_out, int out_size, void* d_ws, size_t ws_size,
                              hipStream_t stream)
{
    const float* x      = (const float*)d_in[0];
    const float* Wg     = (const float*)d_in[1];
    const float* bg     = (const float*)d_in[2];
    const float* b_gate = (const float*)d_in[3];
    const float* b_dec  = (const float*)d_in[4];
    const float* Wenc   = (const float*)d_in[5];
    const float* benc   = (const float*)d_in[6];
    float* out = (float*)d_out;

    char* ws = (char*)d_ws;
    int*      counts  = (int*)(ws + 0);
    int*      offsets = (int*)(ws + 256);
    int*      pairTok = (int*)(ws + 512);
    float*    pairW   = (float*)(ws + 262656);
    int*      tokE    = (int*)(ws + 524800);
    int*      tokSlot = (int*)(ws + 557568);
    float*    f       = (float*)(ws + 590336);
    float*    tmp     = f;   // overlaid: f is dead after select_kernel
    _Float16* xh      = (_Float16*)(ws + 50921984);
    _Float16* Wench   = (_Float16*)(ws + 57213440);
    _Float16* Wdech   = (_Float16*)(ws + 94962176);
    float*    selVal  = (float*)(ws + 132710912);
    int*      selIdx  = (int*)(ws + 134808064);
    int*      selCnt  = (int*)(ws + 136905216);
    int*      pairE   = (int*)(ws + 136937984);
    int*      pairT2  = (int*)(ws + 136970752);
    float*    pw      = (float*)(ws + 137003520);
    float*    tokW    = (float*)(ws + 137036288);

    hipMemsetAsync(counts, 0, 64, stream);
    convx_kernel<<<3072, 256, 0, stream>>>(x, b_dec, xh);
    convwd_kernel<<<(EE*KDD)/4, 256, 0, stream>>>(Wenc, Wench, Wdech);
    gate_kernel<<<BB/4, 256, 0, stream>>>(x, Wg, bg, b_gate, tokE, tokW);
    route_kernel<<<TOTP/1024, 1024, 0, stream>>>(tokE, tokW, counts, pairTok, pairW, tokSlot);
    offsets_kernel<<<1, 64, 0, stream>>>(counts, offsets);
    pair_meta_kernel<<<TOTP/256, 256, 0, stream>>>(tokE, tokSlot, pairW, offsets, pairE, pairT2, pw);
    encode_kernel<<<dim3(KDD/TN, BB/TM, EE), 256, 0, stream>>>(xh, Wench, benc,
                                                               counts, offsets, pairTok, pairW, f);
    select_kernel<<<TOTP/4, 256, 0, stream>>>(f, x, b_dec, Wenc, benc,
                                              pairE, pairT2, pw, selVal, selIdx, selCnt);
    gather_kernel<<<dim3(8, 320), 256, 0, stream>>>(selVal, selIdx, selCnt,
                                                    offsets, Wdech, tmp);
    combine_kernel<<<BB/4, 256, 0, stream>>>(tmp, b_dec, tokE, tokSlot, offsets, out);
}

// Round 8
// 372.453 us; speedup vs baseline: 1.2404x; 1.0919x over previous
//
#include <hip/hip_runtime.h>

// Problem constants (fixed by the reference)
#define BB   4096
#define DD   768
#define EE   16
#define KDD  1536
#define KSEL 50
#define TOTP (2*BB)          // total routed pairs (top-2, distinct experts)
#define FLTEPS 1.1920929e-07f

// Encode GEMM tiling
#define TM 128
#define TN 128

typedef _Float16 half8  __attribute__((ext_vector_type(8)));
typedef _Float16 half4v __attribute__((ext_vector_type(4)));
typedef float    floatx4 __attribute__((ext_vector_type(4)));

// ---------------- workspace layout (bytes) ----------------
// counts  : int[16]              @ 0          (memset to 0 each launch)
// offsets : int[17]              @ 256
// pairTok : int[EE*BB]           @ 512
// pairW   : float[EE*BB]         @ 262656
// tokE    : int[2*BB]            @ 524800
// tokSlot : int[2*BB]            @ 557568
// f       : float[TOTP*KDD]      @ 590336     (50.3 MB)  [gather overlays tmp here]
// xh      : f16[BB*DD]           @ 50921984   (6.3 MB)
// Wench   : f16[EE*KDD*DD]       @ 57213440   (37.7 MB)
// Wdech   : f16[EE*KDD*DD]       @ 94962176   (37.7 MB)
// selVal  : float[TOTP*64]       @ 132710912  (2 MB)
// selIdx  : int[TOTP*64]         @ 134808064  (2 MB)
// selCnt  : int[TOTP]            @ 136905216
// pairE   : int[TOTP]            @ 136937984
// pairT2  : int[TOTP]            @ 136970752
// pw      : float[TOTP]          @ 137003520
// tokW    : float[2*BB]          @ 137036288
// corr    : float[16]            @ 137069056
// total ~137.1 MB

// ================= conversion kernels =================
__global__ __launch_bounds__(256) void convx_kernel(
    const float* __restrict__ x, const float* __restrict__ b_dec,
    _Float16* __restrict__ xh)
{
    int g = blockIdx.x * 256 + threadIdx.x;
    int c4 = g % (DD / 4);
    float4 v = reinterpret_cast<const float4*>(x)[g];
    float4 b = reinterpret_cast<const float4*>(b_dec)[c4];
    half4v h;
    h[0] = (_Float16)(v.x - b.x); h[1] = (_Float16)(v.y - b.y);
    h[2] = (_Float16)(v.z - b.z); h[3] = (_Float16)(v.w - b.w);
    reinterpret_cast<half4v*>(xh)[g] = h;
}

// Fused: read Wenc once, emit Wench (f16 copy) and Wdech (f16, unit-norm rows).
__global__ __launch_bounds__(256) void convwd_kernel(
    const float* __restrict__ Wenc,
    _Float16* __restrict__ Wench, _Float16* __restrict__ Wdech)
{
    const int lane = threadIdx.x & 63;
    const int row  = blockIdx.x * 4 + (threadIdx.x >> 6);
    const float* src = Wenc + (size_t)row * DD;

    float4 v[3];
    float ss = 0.f;
    #pragma unroll
    for (int c = 0; c < 3; ++c) {
        v[c] = *reinterpret_cast<const float4*>(src + c*256 + lane*4);
        ss += v[c].x*v[c].x + v[c].y*v[c].y + v[c].z*v[c].z + v[c].w*v[c].w;
    }
    #pragma unroll
    for (int o = 32; o > 0; o >>= 1) ss += __shfl_xor(ss, o, 64);
    float rn = 1.f / (sqrtf(ss) + FLTEPS);

    _Float16* de = Wench + (size_t)row * DD;
    _Float16* dd = Wdech + (size_t)row * DD;
    #pragma unroll
    for (int c = 0; c < 3; ++c) {
        half4v he, hd;
        he[0] = (_Float16)v[c].x;      he[1] = (_Float16)v[c].y;
        he[2] = (_Float16)v[c].z;      he[3] = (_Float16)v[c].w;
        hd[0] = (_Float16)(v[c].x*rn); hd[1] = (_Float16)(v[c].y*rn);
        hd[2] = (_Float16)(v[c].z*rn); hd[3] = (_Float16)(v[c].w*rn);
        *reinterpret_cast<half4v*>(de + c*256 + lane*4) = he;
        *reinterpret_cast<half4v*>(dd + c*256 + lane*4) = hd;
    }
}

// ================= Kernel 0: gate correction vector =================
// corr[e] = bg[e] - b_gate . Wg[e]   (so logit = x.Wg[e] + corr[e])
__global__ __launch_bounds__(64) void gatecorr_kernel(
    const float* __restrict__ Wg, const float* __restrict__ bg,
    const float* __restrict__ b_gate, float* __restrict__ corr)
{
    const int lane = threadIdx.x;
    const int grp  = lane >> 2;
    const int li   = lane & 3;
    const float4* gr4 = reinterpret_cast<const float4*>(b_gate + li * 192);
    const float4* wr4 = reinterpret_cast<const float4*>(Wg + grp * DD + li * 192);
    float s = 0.f;
    #pragma unroll
    for (int i = 0; i < 48; ++i) {
        float4 b = gr4[i], w = wr4[i];
        s = fmaf(b.x, w.x, s); s = fmaf(b.y, w.y, s);
        s = fmaf(b.z, w.z, s); s = fmaf(b.w, w.w, s);
    }
    s += __shfl_xor(s, 1, 64);
    s += __shfl_xor(s, 2, 64);
    if (li == 0) corr[grp] = bg[grp] - s;
}

// ================= Kernel 1: gating — LDS-staged, thread-per-(token,expert) =================
// 256 blocks x 256 threads; block = 16 tokens. Wg + 16 x-rows staged to LDS
// (row stride 193 float4 = +4 float pad -> Wg reads are 2-way bank aliased = free).
__global__ __launch_bounds__(256) void gate_kernel(
    const float* __restrict__ x, const float* __restrict__ Wg,
    const float* __restrict__ bg, const float* __restrict__ b_gate,
    const float* __restrict__ corr,
    int* __restrict__ tokE, float* __restrict__ tokW)
{
    __shared__ float4 wgS[16 * 193];
    __shared__ float4 xsS[16 * 193];
    __shared__ float  lgS[16][16];

    const int tid = threadIdx.x;
    const int t0  = blockIdx.x * 16;

    // stage Wg (3072 float4) and x rows (3072 float4), coalesced
    const float4* wg4 = reinterpret_cast<const float4*>(Wg);
    const float4* xx4 = reinterpret_cast<const float4*>(x + (size_t)t0 * DD);
    #pragma unroll
    for (int k = 0; k < 12; ++k) {
        int g = tid + 256 * k;            // 0..3071
        int row = g / 192, d4 = g % 192;
        wgS[row * 193 + d4] = wg4[g];
        xsS[row * 193 + d4] = xx4[g];
    }
    __syncthreads();

    // thread (tt, e) computes logit[tt][e]
    {
        const int tt = tid >> 4;
        const int e  = tid & 15;
        const float4* xp = &xsS[tt * 193];
        const float4* wp = &wgS[e * 193];
        float a0 = 0.f, a1 = 0.f, a2 = 0.f, a3 = 0.f;
        #pragma unroll 4
        for (int d4 = 0; d4 < 192; d4 += 4) {
            float4 v0 = xp[d4+0], w0 = wp[d4+0];
            float4 v1 = xp[d4+1], w1 = wp[d4+1];
            float4 v2 = xp[d4+2], w2 = wp[d4+2];
            float4 v3 = xp[d4+3], w3 = wp[d4+3];
            a0 = fmaf(v0.x,w0.x, fmaf(v0.y,w0.y, fmaf(v0.z,w0.z, fmaf(v0.w,w0.w, a0))));
            a1 = fmaf(v1.x,w1.x, fmaf(v1.y,w1.y, fmaf(v1.z,w1.z, fmaf(v1.w,w1.w, a1))));
            a2 = fmaf(v2.x,w2.x, fmaf(v2.y,w2.y, fmaf(v2.z,w2.z, fmaf(v2.w,w2.w, a2))));
            a3 = fmaf(v3.x,w3.x, fmaf(v3.y,w3.y, fmaf(v3.z,w3.z, fmaf(v3.w,w3.w, a3))));
        }
        lgS[tt][e] = (a0 + a1) + (a2 + a3) + corr[e];
    }
    __syncthreads();

    // epilogue: each wave handles 4 tokens; all lanes redundantly compute top-2
    const int lane = tid & 63;
    const int wv   = tid >> 6;
    for (int k = 0; k < 4; ++k) {
        const int tl = wv * 4 + k;       // token within block
        const int t  = t0 + tl;

        float lg[16];
        #pragma unroll
        for (int e = 0; e < 16; ++e) lg[e] = lgS[tl][e];

        int i1 = 0;
        #pragma unroll
        for (int e = 1; e < 16; ++e) if (lg[e] > lg[i1]) i1 = e;
        int i2 = (i1 == 0) ? 1 : 0;
        #pragma unroll
        for (int e = 0; e < 16; ++e) if (e != i1 && lg[e] > lg[i2]) i2 = e;
        float l3 = -1e30f;
        #pragma unroll
        for (int e = 0; e < 16; ++e) if (e != i1 && e != i2) l3 = fmaxf(l3, lg[e]);

        // near-tie at the 2-vs-3 boundary: refine all logits in fp64 (rare)
        if (lg[i2] - l3 < 1e-4f) {
            const float* xr = x + (size_t)t * DD;
            float xv[12];
            #pragma unroll
            for (int q = 0; q < 12; ++q) xv[q] = xr[lane + 64*q] - b_gate[lane + 64*q];
            #pragma unroll
            for (int e = 0; e < 16; ++e) {
                const float* wr = Wg + e * DD;
                double sd = 0.0;
                #pragma unroll
                for (int q = 0; q < 12; ++q) sd += (double)xv[q] * (double)wr[lane + 64*q];
                #pragma unroll
                for (int o = 32; o > 0; o >>= 1) sd += __shfl_xor(sd, o, 64);
                lg[e] = (float)(sd + (double)bg[e]);
            }
            i1 = 0;
            for (int e = 1; e < 16; ++e) if (lg[e] > lg[i1]) i1 = e;
            i2 = (i1 == 0) ? 1 : 0;
            for (int e = 0; e < 16; ++e) if (e != i1 && lg[e] > lg[i2]) i2 = e;
        }

        float mx = lg[0];
        #pragma unroll
        for (int e = 1; e < 16; ++e) mx = fmaxf(mx, lg[e]);
        float S = 0.f;
        #pragma unroll
        for (int e = 0; e < 16; ++e) S += expf(lg[e] - mx);
        float p1 = expf(lg[i1] - mx) / S;
        float p2 = expf(lg[i2] - mx) / S;
        float ed = expf(p2 - p1);
        float m1 = 1.f / (1.f + ed);
        float m2 = ed / (1.f + ed);

        if (lane == 0) {
            tokE[2*t + 0] = i1;  tokW[2*t + 0] = m1;
            tokE[2*t + 1] = i2;  tokW[2*t + 1] = m2;
        }
    }
}

// ================= Kernel 1b: routing via LDS histogram (128 global atomics total) =================
__global__ __launch_bounds__(1024) void route_kernel(
    const int* __restrict__ tokE, const float* __restrict__ tokW,
    int* __restrict__ counts, int* __restrict__ pairTok,
    float* __restrict__ pairW, int* __restrict__ tokSlot)
{
    __shared__ int hist[EE];
    __shared__ int base[EE];
    const int tid = threadIdx.x;
    if (tid < EE) hist[tid] = 0;
    __syncthreads();

    const int i = blockIdx.x * 1024 + tid;       // pair id = 2t+j
    const int e = tokE[i];
    const int lr = atomicAdd(&hist[e], 1);       // LDS atomic — bank-local
    __syncthreads();

    if (tid < EE) base[tid] = atomicAdd(&counts[tid], hist[tid]);
    __syncthreads();

    const int slot = base[e] + lr;
    pairTok[e * BB + slot] = i >> 1;
    pairW[e * BB + slot]   = tokW[i];
    tokSlot[i] = slot;
}

// ================= Kernel 2: prefix offsets =================
__global__ void offsets_kernel(const int* __restrict__ counts, int* __restrict__ offsets)
{
    if (threadIdx.x == 0) {
        int s = 0;
        for (int e = 0; e < EE; ++e) { offsets[e] = s; s += counts[e]; }
        offsets[EE] = s;
    }
}

// ================= Kernel 2b: compact pair metadata =================
__global__ __launch_bounds__(256) void pair_meta_kernel(
    const int* __restrict__ tokE, const int* __restrict__ tokSlot,
    const float* __restrict__ pairW, const int* __restrict__ offsets,
    int* __restrict__ pairE, int* __restrict__ pairT2, float* __restrict__ pw)
{
    int i = blockIdx.x * 256 + threadIdx.x;
    if (i >= TOTP) return;
    int t = i >> 1, j = i & 1;
    int e = tokE[2*t + j], slot = tokSlot[2*t + j];
    int p = offsets[e] + slot;
    pairE[p] = e;
    pairT2[p] = t;
    pw[p] = pairW[e * BB + slot];
}

// ================= Kernel 3: grouped f16 MFMA encode GEMM =================
__global__ __launch_bounds__(256) void encode_kernel(
    const _Float16* __restrict__ xh, const _Float16* __restrict__ Wench,
    const float* __restrict__ benc,
    const int* __restrict__ counts, const int* __restrict__ offsets,
    const int* __restrict__ pairTok, const float* __restrict__ pairW,
    float* __restrict__ f)
{
    const int e     = blockIdx.z;
    const int count = counts[e];
    const int m0    = blockIdx.y * TM;
    if (m0 >= count) return;
    const int n0 = blockIdx.x * TN;

    __shared__ __align__(16) _Float16 As[128][32];
    __shared__ __align__(16) _Float16 Bs[128][32];
    __shared__ int   toks[TM];
    __shared__ float wls[TM];

    const int tid = threadIdx.x;
    if (tid < TM) {
        int mg = m0 + tid;
        toks[tid] = (mg < count) ? pairTok[e * BB + mg] : -1;
        wls[tid]  = (mg < count) ? pairW[e * BB + mg] : 0.f;
    }
    __syncthreads();

    const int srow = tid >> 1;
    const int sseg = (tid & 1) * 16;
    const int tok  = toks[srow];
    const _Float16* arow = xh + (size_t)(tok < 0 ? 0 : tok) * DD + sseg;
    const _Float16* brow = Wench + ((size_t)e * KDD + n0 + srow) * DD + sseg;

    const int lane = tid & 63;
    const int wv   = tid >> 6;
    const int rb   = (wv >> 1) * 64;
    const int cb   = (wv & 1) * 64;
    const int lc   = lane & 15;
    const int lq   = lane >> 4;

    floatx4 acc[4][4];
    #pragma unroll
    for (int mi = 0; mi < 4; ++mi)
        #pragma unroll
        for (int nj = 0; nj < 4; ++nj)
            acc[mi][nj] = (floatx4){0.f, 0.f, 0.f, 0.f};

    for (int kt = 0; kt < DD / 32; ++kt) {
        const int koff = kt * 32;
        uint4 a0, a1, b0, b1;
        if (tok >= 0) {
            a0 = *reinterpret_cast<const uint4*>(arow + koff);
            a1 = *reinterpret_cast<const uint4*>(arow + koff + 8);
        } else {
            a0 = make_uint4(0,0,0,0); a1 = make_uint4(0,0,0,0);
        }
        b0 = *reinterpret_cast<const uint4*>(brow + koff);
        b1 = *reinterpret_cast<const uint4*>(brow + koff + 8);
        __syncthreads();
        *reinterpret_cast<uint4*>(&As[srow][sseg])     = a0;
        *reinterpret_cast<uint4*>(&As[srow][sseg + 8]) = a1;
        *reinterpret_cast<uint4*>(&Bs[srow][sseg])     = b0;
        *reinterpret_cast<uint4*>(&Bs[srow][sseg + 8]) = b1;
        __syncthreads();

        half8 af[4], bf[4];
        #pragma unroll
        for (int mi = 0; mi < 4; ++mi)
            af[mi] = *reinterpret_cast<const half8*>(&As[rb + mi*16 + lc][lq * 8]);
        #pragma unroll
        for (int nj = 0; nj < 4; ++nj)
            bf[nj] = *reinterpret_cast<const half8*>(&Bs[cb + nj*16 + lc][lq * 8]);
        #pragma unroll
        for (int mi = 0; mi < 4; ++mi)
            #pragma unroll
            for (int nj = 0; nj < 4; ++nj)
                acc[mi][nj] = __builtin_amdgcn_mfma_f32_16x16x32_f16(af[mi], bf[nj], acc[mi][nj], 0, 0, 0);
    }

    const int off = offsets[e];
    float bv[4];
    #pragma unroll
    for (int nj = 0; nj < 4; ++nj)
        bv[nj] = benc[e * KDD + n0 + cb + nj*16 + lc];

    #pragma unroll
    for (int mi = 0; mi < 4; ++mi) {
        #pragma unroll
        for (int r = 0; r < 4; ++r) {
            int ml = rb + mi*16 + lq*4 + r;
            int mg = m0 + ml;
            if (mg < count) {
                float wrow = wls[ml];
                float* frow = f + (size_t)(off + mg) * KDD + n0 + cb;
                #pragma unroll
                for (int nj = 0; nj < 4; ++nj)
                    frow[nj*16 + lc] = wrow * fmaxf(acc[mi][nj][r] + bv[nj], 0.f);
            }
        }
    }
}

// ================= Kernel 4a: top-50 selection per pair =================
__global__ __launch_bounds__(256) void select_kernel(
    const float* __restrict__ f, const float* __restrict__ x,
    const float* __restrict__ b_dec, const float* __restrict__ Wenc,
    const float* __restrict__ benc,
    const int* __restrict__ pairE, const int* __restrict__ pairT2,
    const float* __restrict__ pw,
    float* __restrict__ selVal, int* __restrict__ selIdx, int* __restrict__ selCnt)
{
    const int lane = threadIdx.x & 63;
    const int wv   = threadIdx.x >> 6;
    const int p    = blockIdx.x * 4 + wv;

    __shared__ float dvS[4][56];
    __shared__ int   diS[4][56];
    __shared__ float cvS[4][24];
    __shared__ int   ciS[4][24];
    __shared__ int   cntS[4][2];

    const int e   = pairE[p];
    const int t   = pairT2[p];
    const float w = pw[p];
    const float* fr = f + (size_t)p * KDD;

    float v[24];
    #pragma unroll
    for (int q = 0; q < 24; ++q) v[q] = fr[lane + 64*q];

    float mxv = 0.f; int cp = 0;
    #pragma unroll
    for (int q = 0; q < 24; ++q) {
        mxv = fmaxf(mxv, v[q]);
        cp += __popcll(__ballot(v[q] > 0.f));
    }
    #pragma unroll
    for (int o = 32; o > 0; o >>= 1) mxv = fmaxf(mxv, __shfl_xor(mxv, o, 64));

    const bool simple = (cp <= KSEL);
    const float E = w * 6e-3f;                  // 15 sigma of f16-MFMA z-noise
    float lo = 0.f, hi = mxv;
    if (!simple) {
        for (int it = 0; it < 32 && (hi - lo) > 0.5f * E; ++it) {
            float mid = 0.5f * (lo + hi);
            int c = 0;
            #pragma unroll
            for (int q = 0; q < 24; ++q) c += __popcll(__ballot(v[q] > mid));
            if (c > KSEL)      lo = mid;
            else if (c < KSEL) hi = mid;
            else { lo = mid; hi = mid; break; }
        }
    }

    if (lane == 0) { cntS[wv][0] = 0; cntS[wv][1] = 0; }
    __syncthreads();

    if (simple) {
        #pragma unroll
        for (int q = 0; q < 24; ++q)
            if (v[q] > 0.f) {
                int pp = atomicAdd(&cntS[wv][0], 1);
                if (pp < 56) { dvS[wv][pp] = v[q]; diS[wv][pp] = lane + 64*q; }
            }
    } else {
        const float thD = hi + 2.f * E;
        const float thC = lo - 2.f * E;
        #pragma unroll
        for (int q = 0; q < 24; ++q) {
            float vq = v[q];
            if (vq > thD) {
                int pp = atomicAdd(&cntS[wv][0], 1);
                if (pp < 56) { dvS[wv][pp] = vq; diS[wv][pp] = lane + 64*q; }
            } else if (vq > thC) {
                int pp = atomicAdd(&cntS[wv][1], 1);
                if (pp < 24) { cvS[wv][pp] = vq; ciS[wv][pp] = lane + 64*q; }
            }
        }
    }
    __syncthreads();

    int nD = cntS[wv][0]; if (nD > 56) nD = 56;
    int nC = cntS[wv][1]; if (nC > 24) nC = 24;
    int need = simple ? 0 : (KSEL - nD);
    if (need < 0) need = 0;
    if (need > nC) need = nC;

    unsigned long long cmask = 0ull;
    if (need > 0 && need < nC) {
        const float* xr = x + (size_t)t * DD;
        double myz = -1.0e300;
        int myidx = 0x7fffffff;
        for (int c = 0; c < nC; ++c) {
            int idx = ciS[wv][c];
            const float* wr = Wenc + ((size_t)e * KDD + idx) * DD;
            double s = 0.0;
            #pragma unroll
            for (int d = 0; d < 12; ++d)
                s += ((double)xr[lane + 64*d] - (double)b_dec[lane + 64*d]) * (double)wr[lane + 64*d];
            #pragma unroll
            for (int o = 32; o > 0; o >>= 1) s += __shfl_xor(s, o, 64);
            if (lane == c) { myz = s + (double)benc[e * KDD + idx]; myidx = idx; }
        }
        bool used = false;
        for (int s2 = 0; s2 < need; ++s2) {
            bool pres = (lane < nC) && !used;
            double bz = pres ? myz : -1.0e301;
            int bl = pres ? lane : 127;
            int bi = pres ? myidx : 0x7fffffff;
            #pragma unroll
            for (int o = 32; o > 0; o >>= 1) {
                double oz = __shfl_xor(bz, o, 64);
                int    ol = __shfl_xor(bl, o, 64);
                int    oi = __shfl_xor(bi, o, 64);
                if (oz > bz || (oz == bz && oi < bi)) { bz = oz; bl = ol; bi = oi; }
            }
            if (lane == bl) used = true;
            if (bl < 64) cmask |= (1ull << bl);
        }
    } else if (need == nC && nC > 0) {
        cmask = (1ull << nC) - 1ull;
    }

    if (lane == 0) {
        int k = nD; if (k > KSEL) k = KSEL;
        for (int c = 0; c < nC && k < KSEL; ++c)
            if ((cmask >> c) & 1ull) { dvS[wv][k] = cvS[wv][c]; diS[wv][k] = ciS[wv][c]; ++k; }
        cntS[wv][0] = k;
    }
    __syncthreads();

    int cnt = cntS[wv][0];
    if (lane < cnt) {
        selVal[(size_t)p * 64 + lane] = dvS[wv][lane];
        selIdx[(size_t)p * 64 + lane] = diS[wv][lane];
    }
    if (lane == 0) selCnt[p] = cnt;
}

// ================= Kernel 4b: expert-grouped gather, 8-row unroll, no atomics =================
__global__ __launch_bounds__(256) void gather_kernel(
    const float* __restrict__ selVal, const int* __restrict__ selIdx,
    const int* __restrict__ selCnt, const int* __restrict__ offsets,
    const _Float16* __restrict__ Wdech, float* __restrict__ tmp)
{
    const int lane = threadIdx.x & 63;
    const int wv   = threadIdx.x >> 6;
    const int xg   = blockIdx.x;
    const int base = offsets[2*xg];
    const int mid  = offsets[2*xg + 1];
    const int end  = offsets[2*xg + 2];
    const int cntg = end - base;

    for (int pl = blockIdx.y * 4 + wv; pl < cntg; pl += gridDim.y * 4) {
        const int p   = base + pl;
        const int e   = (p < mid) ? (2*xg) : (2*xg + 1);
        const int cnt = selCnt[p];

        float myVal = 0.f; int myIdx = 0;
        if (lane < cnt) {
            myVal = selVal[(size_t)p * 64 + lane];
            myIdx = selIdx[(size_t)p * 64 + lane];
        }

        const _Float16* wb = Wdech + (size_t)e * KDD * DD;
        float acc[12];
        #pragma unroll
        for (int k = 0; k < 12; ++k) acc[k] = 0.f;

        const int padded = (cnt + 7) & ~7;
        for (int r = 0; r < padded; r += 8) {
            float vv[8];
            const _Float16* rp[8];
            #pragma unroll
            for (int u = 0; u < 8; ++u) {
                vv[u] = __shfl(myVal, r + u);
                int iu = __shfl(myIdx, r + u);
                rp[u] = wb + (size_t)iu * DD + lane * 4;
            }
            half4v h[8][3];
            #pragma unroll
            for (int u = 0; u < 8; ++u) {
                h[u][0] = *reinterpret_cast<const half4v*>(rp[u]);
                h[u][1] = *reinterpret_cast<const half4v*>(rp[u] + 256);
                h[u][2] = *reinterpret_cast<const half4v*>(rp[u] + 512);
            }
            #pragma unroll
            for (int u = 0; u < 8; ++u)
                #pragma unroll
                for (int c = 0; c < 3; ++c)
                    #pragma unroll
                    for (int k = 0; k < 4; ++k)
                        acc[c*4 + k] = fmaf(vv[u], (float)h[u][c][k], acc[c*4 + k]);
        }

        float* orow = tmp + (size_t)p * DD + lane * 4;
        #pragma unroll
        for (int c = 0; c < 3; ++c) {
            float4 o = make_float4(acc[c*4+0], acc[c*4+1], acc[c*4+2], acc[c*4+3]);
            *reinterpret_cast<float4*>(orow + c * 256) = o;
        }
    }
}

// ================= Kernel 4c: combine two pair rows + b_dec -> out =================
__global__ __launch_bounds__(256) void combine_kernel(
    const float* __restrict__ tmp, const float* __restrict__ b_dec,
    const int* __restrict__ tokE, const int* __restrict__ tokSlot,
    const int* __restrict__ offsets, float* __restrict__ out)
{
    const int lane = threadIdx.x & 63;
    const int t    = blockIdx.x * 4 + (threadIdx.x >> 6);

    const int p0 = offsets[tokE[2*t + 0]] + tokSlot[2*t + 0];
    const int p1 = offsets[tokE[2*t + 1]] + tokSlot[2*t + 1];

    const float* r0 = tmp + (size_t)p0 * DD + lane * 4;
    const float* r1 = tmp + (size_t)p1 * DD + lane * 4;
    float* orow = out + (size_t)t * DD + lane * 4;
    #pragma unroll
    for (int c = 0; c < 3; ++c) {
        float4 a = *reinterpret_cast<const float4*>(r0 + c * 256);
        float4 b = *reinterpret_cast<const float4*>(r1 + c * 256);
        float4 d = *reinterpret_cast<const float4*>(b_dec + c * 256 + lane * 4);
        *reinterpret_cast<float4*>(orow + c * 256) =
            make_float4(a.x + b.x + d.x, a.y + b.y + d.y, a.z + b.z + d.z, a.w + b.w + d.w);
    }
}

// ================= host launcher =================
extern "C" void kernel_launch(void* const* d_in, const int* in_sizes, int n_in,
                              void* d_out, int out_size, void* d_ws, size_t ws_size,
                              hipStream_t stream)
{
    const float* x      = (const float*)d_in[0];
    const float* Wg     = (const float*)d_in[1];
    const float* bg     = (const float*)d_in[2];
    const float* b_gate = (const float*)d_in[3];
    const float* b_dec  = (const float*)d_in[4];
    const float* Wenc   = (const float*)d_in[5];
    const float* benc   = (const float*)d_in[6];
    float* out = (float*)d_out;

    char* ws = (char*)d_ws;
    int*      counts  = (int*)(ws + 0);
    int*      offsets = (int*)(ws + 256);
    int*      pairTok = (int*)(ws + 512);
    float*    pairW   = (float*)(ws + 262656);
    int*      tokE    = (int*)(ws + 524800);
    int*      tokSlot = (int*)(ws + 557568);
    float*    f       = (float*)(ws + 590336);
    float*    tmp     = f;   // overlaid: f is dead after select_kernel
    _Float16* xh      = (_Float16*)(ws + 50921984);
    _Float16* Wench   = (_Float16*)(ws + 57213440);
    _Float16* Wdech   = (_Float16*)(ws + 94962176);
    float*    selVal  = (float*)(ws + 132710912);
    int*      selIdx  = (int*)(ws + 134808064);
    int*      selCnt  = (int*)(ws + 136905216);
    int*      pairE   = (int*)(ws + 136937984);
    int*      pairT2  = (int*)(ws + 136970752);
    float*    pw      = (float*)(ws + 137003520);
    float*    tokW    = (float*)(ws + 137036288);
    float*    corr    = (float*)(ws + 137069056);

    hipMemsetAsync(counts, 0, 64, stream);
    gatecorr_kernel<<<1, 64, 0, stream>>>(Wg, bg, b_gate, corr);
    convx_kernel<<<3072, 256, 0, stream>>>(x, b_dec, xh);
    convwd_kernel<<<(EE*KDD)/4, 256, 0, stream>>>(Wenc, Wench, Wdech);
    gate_kernel<<<BB/16, 256, 0, stream>>>(x, Wg, bg, b_gate, corr, tokE, tokW);
    route_kernel<<<TOTP/1024, 1024, 0, stream>>>(tokE, tokW, counts, pairTok, pairW, tokSlot);
    offsets_kernel<<<1, 64, 0, stream>>>(counts, offsets);
    pair_meta_kernel<<<TOTP/256, 256, 0, stream>>>(tokE, tokSlot, pairW, offsets, pairE, pairT2, pw);
    encode_kernel<<<dim3(KDD/TN, BB/TM, EE), 256, 0, stream>>>(xh, Wench, benc,
                                                               counts, offsets, pairTok, pairW, f);
    select_kernel<<<TOTP/4, 256, 0, stream>>>(f, x, b_dec, Wenc, benc,
                                              pairE, pairT2, pw, selVal, selIdx, selCnt);
    gather_kernel<<<dim3(8, 320), 256, 0, stream>>>(selVal, selIdx, selCnt,
                                                    offsets, Wdech, tmp);
    combine_kernel<<<BB/4, 256, 0, stream>>>(tmp, b_dec, tokE, tokSlot, offsets, out);
}